// Round 9
// baseline (33.758 us; speedup 1.0000x reference)
//
#include <hip/hip_runtime.h>

// B=8, X=Y=Z=128, f32. out = active * Lap(mu*active) / dx^2, periodic.
// 2.5D register march, 2-deep pipeline, XCD-partitioned by batch sample,
// pincer x-march. R9 change: barrier = s_waitcnt lgkmcnt(0) + raw s_barrier
// (NO vmcnt drain -> plane i+2 loads stay in flight across the barrier),
// and the TX loop is fully unrolled so pipeline register rotation is
// renamed away instead of wait-and-copied.
#define NB 8
#define NX 128
#define NY 128
#define NZ 128

#define TY 32
#define TX 16
#define XC (NX / TX)     // 8
#define YT (NY / TY)     // 4
#define ROWS (TY + 2)    // 34

typedef float f4v __attribute__((ext_vector_type(4)));

#define EMUL(e, m, a) \
    e.x = m.x * a.x; e.y = m.y * a.y; e.z = m.z * a.z; e.w = m.w * a.w;

// LDS-only barrier: ds_writes must be visible block-wide, but global loads
// (register destinations, per-wave private) may remain outstanding.
__device__ __forceinline__ void lds_barrier() {
    asm volatile("s_waitcnt lgkmcnt(0)" ::: "memory");
    __builtin_amdgcn_s_barrier();
}

__global__ __launch_bounds__(1024) void lap_pincer(
    const float* __restrict__ mu,
    const float* __restrict__ act,
    const float* __restrict__ dxp,
    float* __restrict__ out)
{
    __shared__ float buf[2][ROWS][NZ];   // 34816 B

    const int tid = threadIdx.x;         // 0..1023
    const int bid = blockIdx.x;
    const int b  = bid & 7;              // XCD index (round-robin bid%8)
    const int yt = (bid >> 3) & 3;
    const int xc = bid >> 5;

    const int x0 = xc * TX;
    const int y0 = yt * TY;
    const int fwd  = xc & 1;             // odd xc: up; even xc: down
    const int start = fwd ? x0 : x0 + TX - 1;
    const int step  = fwd ? 1 : -1;

    const int planeYZ = NY * NZ;         // 16384
    const int baseB = b * NX * planeYZ;

    const float dxv = dxp[0];
    const float inv = 1.0f / (dxv * dxv);

    const int r  = tid >> 5;             // 0..31
    const int zq = tid & 31;
    const int z0 = zq * 4;
    const int gy = y0 + r;
    const int rowOff = gy * NZ + z0;

    // y-halo duty: first 64 threads -> 2 halo rows x 32 z-quads
    const int hr   = tid >> 5;                       // 0 or 1 (valid tid<64)
    const int hy   = hr ? ((y0 + TY) & (NY - 1)) : ((y0 - 1) & (NY - 1));
    const int hRow = hr ? (TY + 1) : 0;
    const int hOff = hy * NZ + z0;

    float4 eP, eC, aC;        // products planes i-1, i; act plane i
    float4 mN, aN;            // raw mu/act plane i+1 (arrived)
    float4 mNN, aNN;          // raw plane i+2 (in flight)
    float4 hm, ha, hmNN, haNN;

    auto ld = [&](int gx, int off, float4* m, float4* a) {
        const int gIdx = baseB + gx * planeYZ + off;
        *m = *reinterpret_cast<const float4*>(mu + gIdx);
        *a = *reinterpret_cast<const float4*>(act + gIdx);
    };

    // ---- prologue ----
    {
        float4 m0, a0;
        ld((start - step) & (NX - 1), rowOff, &m0, &a0);  // behind plane (regs only)
        EMUL(eP, m0, a0);
        ld(start, rowOff, &m0, &aC);                      // plane 0
        EMUL(eC, m0, aC);
        *reinterpret_cast<float4*>(&buf[0][r + 1][z0]) = eC;
        if (tid < 64) {
            float4 m1, a1, e1;
            ld(start, hOff, &m1, &a1);
            EMUL(e1, m1, a1);
            *reinterpret_cast<float4*>(&buf[0][hRow][z0]) = e1;
        }
        ld(start + step, rowOff, &mN, &aN);               // plane 1 raw
        if (tid < 64) ld(start + step, hOff, &hm, &ha);
        lds_barrier();
    }

    #pragma unroll
    for (int i = 0; i < TX; ++i) {
        // 1) issue loads for plane i+2 (consumed next iter; stay in flight
        //    across the lds_barrier below)
        if (i < TX - 1) {
            const int gx2 = (start + (i + 2) * step) & (NX - 1);
            ld(gx2, rowOff, &mNN, &aNN);
            if (tid < 64) ld(gx2, hOff, &hmNN, &haNN);
        }

        // 2) plane i+1: product + LDS publish (mN/aN issued one iter ago;
        //    compiler inserts counted vmcnt here)
        float4 eN;
        EMUL(eN, mN, aN);
        if (i < TX - 1) {
            *reinterpret_cast<float4*>(&buf[(i + 1) & 1][r + 1][z0]) = eN;
            if (tid < 64) {
                float4 he;
                EMUL(he, hm, ha);
                *reinterpret_cast<float4*>(&buf[(i + 1) & 1][hRow][z0]) = he;
            }
        }

        // 3) compute plane i (x+- sum is symmetric -> direction-agnostic)
        const int s = i & 1;
        float4 eym = *reinterpret_cast<const float4*>(&buf[s][r][z0]);
        float4 eyp = *reinterpret_cast<const float4*>(&buf[s][r + 2][z0]);
        float ezm = __shfl(eC.w, (zq + 31) & 31, 32);
        float ezp = __shfl(eC.x, (zq + 1) & 31, 32);

        float4 o;
        o.x = (eP.x + eN.x + eym.x + eyp.x + ezm  + eC.y - 6.0f * eC.x) * inv * aC.x;
        o.y = (eP.y + eN.y + eym.y + eyp.y + eC.x + eC.z - 6.0f * eC.y) * inv * aC.y;
        o.z = (eP.z + eN.z + eym.z + eyp.z + eC.y + eC.w - 6.0f * eC.z) * inv * aC.z;
        o.w = (eP.w + eN.w + eym.w + eyp.w + eC.z + ezp  - 6.0f * eC.w) * inv * aC.w;

        const int gIdx = baseB + (start + i * step) * planeYZ + rowOff;
        f4v ov = {o.x, o.y, o.z, o.w};
        __builtin_nontemporal_store(ov, reinterpret_cast<f4v*>(out + gIdx));

        // 4) rotate pipeline state (renamed away by full unroll)
        eP = eC; eC = eN; aC = aN;
        mN = mNN; aN = aNN; hm = hmNN; ha = haNN;

        lds_barrier();   // LDS visibility only; global loads stay in flight
    }
}

extern "C" void kernel_launch(void* const* d_in, const int* in_sizes, int n_in,
                              void* d_out, int out_size, void* d_ws, size_t ws_size,
                              hipStream_t stream) {
    const float* mu  = (const float*)d_in[0];
    const float* act = (const float*)d_in[1];
    const float* dx  = (const float*)d_in[2];
    float* out = (float*)d_out;

    const int grid = NB * YT * XC;   // 256 blocks, 1024 threads each
    lap_pincer<<<grid, 1024, 0, stream>>>(mu, act, dx, out);
}